// Round 6
// baseline (17387.978 us; speedup 1.0000x reference)
//
#include <hip/hip_runtime.h>
#include <cmath>

#define B_ 32
#define T_ 512
#define W_ 250
#define D_ 768
#define H_ 768
#define G_ 3072   // 4*H
#define NT_ 2

// ============================ first-subtoken gather ============================
__global__ void first_idx_kernel(const int* __restrict__ words_ids, int* __restrict__ fidx,
                                 unsigned int* __restrict__ counter) {
  int i = blockIdx.x * blockDim.x + threadIdx.x;
  if (blockIdx.x == 0 && threadIdx.x == 0) *counter = 0u;  // zero the grid-barrier counter
  if (i >= B_ * W_) return;
  int b = i / W_, w = i % W_;
  const int* row = words_ids + (size_t)b * T_;
  int idx = T_ - 1;
  for (int t = 0; t < T_; ++t) {
    if (row[t] == w) { idx = t; break; }
  }
  fidx[i] = idx;
}

// feat layout: [W][B][D]  (time-major so a time-chunk is contiguous GEMM rows)
__global__ void gather_kernel(const float* __restrict__ bert_out, const int* __restrict__ fidx,
                              float* __restrict__ feat) {
  int i = blockIdx.x * blockDim.x + threadIdx.x;
  const int nv = D_ / 4;
  if (i >= B_ * W_ * nv) return;
  int bw = i / nv, d4 = i % nv;
  int b = bw / W_, w = bw % W_;
  int t = fidx[bw];
  float4 v = ((const float4*)(bert_out + ((size_t)b * T_ + t) * D_))[d4];
  ((float4*)(feat + ((size_t)w * B_ + b) * D_))[d4] = v;
}

// ============================ fp32 GEMM: C[M,N] = A[M,K] * B[N,K]^T + bias[N] ============================
__global__ __launch_bounds__(256) void gemm_bias_kernel(
    const float* __restrict__ A, const float* __restrict__ Bm,
    const float* __restrict__ bias, float* __restrict__ C,
    int M, int N, int K) {
  __shared__ float As[2][16][132];
  __shared__ float Bs[2][16][132];
  const int tid = threadIdx.x;
  const int row0 = blockIdx.x * 128;
  const int col0 = blockIdx.y * 128;
  const int tx = tid & 15;       // N dim of microtile
  const int ty = tid >> 4;       // M dim of microtile
  const int lr = tid >> 1;       // 0..127 : tile row this thread loads
  const int lk = (tid & 1) * 8;  // k offset 0 or 8

  int ar = row0 + lr;
  if (ar >= M) ar = M - 1;                 // clamp (results of padded rows never stored)
  const float* __restrict__ Ap = A + (size_t)ar * K + lk;
  const float* __restrict__ Bp = Bm + (size_t)(col0 + lr) * K + lk;

  float acc[8][8];
#pragma unroll
  for (int i = 0; i < 8; ++i)
#pragma unroll
    for (int j = 0; j < 8; ++j) acc[i][j] = 0.0f;

  const int nk = K >> 4;

  {
    float4 a0 = *(const float4*)(Ap + 0);
    float4 a1 = *(const float4*)(Ap + 4);
    float4 b0 = *(const float4*)(Bp + 0);
    float4 b1 = *(const float4*)(Bp + 4);
    As[0][lk + 0][lr] = a0.x; As[0][lk + 1][lr] = a0.y; As[0][lk + 2][lr] = a0.z; As[0][lk + 3][lr] = a0.w;
    As[0][lk + 4][lr] = a1.x; As[0][lk + 5][lr] = a1.y; As[0][lk + 6][lr] = a1.z; As[0][lk + 7][lr] = a1.w;
    Bs[0][lk + 0][lr] = b0.x; Bs[0][lk + 1][lr] = b0.y; Bs[0][lk + 2][lr] = b0.z; Bs[0][lk + 3][lr] = b0.w;
    Bs[0][lk + 4][lr] = b1.x; Bs[0][lk + 5][lr] = b1.y; Bs[0][lk + 6][lr] = b1.z; Bs[0][lk + 7][lr] = b1.w;
  }
  __syncthreads();

  for (int t = 0; t < nk; ++t) {
    const int cur = t & 1;
    float4 a0, a1, b0, b1;
    const bool pf = (t + 1 < nk);
    if (pf) {
      const int k0 = (t + 1) << 4;
      a0 = *(const float4*)(Ap + k0);
      a1 = *(const float4*)(Ap + k0 + 4);
      b0 = *(const float4*)(Bp + k0);
      b1 = *(const float4*)(Bp + k0 + 4);
    }
#pragma unroll
    for (int k = 0; k < 16; ++k) {
      float a[8], b[8];
      *(float4*)&a[0] = *(const float4*)&As[cur][k][ty * 8];
      *(float4*)&a[4] = *(const float4*)&As[cur][k][ty * 8 + 4];
      *(float4*)&b[0] = *(const float4*)&Bs[cur][k][tx * 8];
      *(float4*)&b[4] = *(const float4*)&Bs[cur][k][tx * 8 + 4];
#pragma unroll
      for (int i = 0; i < 8; ++i)
#pragma unroll
        for (int j = 0; j < 8; ++j) acc[i][j] += a[i] * b[j];
    }
    if (pf) {
      const int nxt = cur ^ 1;
      As[nxt][lk + 0][lr] = a0.x; As[nxt][lk + 1][lr] = a0.y; As[nxt][lk + 2][lr] = a0.z; As[nxt][lk + 3][lr] = a0.w;
      As[nxt][lk + 4][lr] = a1.x; As[nxt][lk + 5][lr] = a1.y; As[nxt][lk + 6][lr] = a1.z; As[nxt][lk + 7][lr] = a1.w;
      Bs[nxt][lk + 0][lr] = b0.x; Bs[nxt][lk + 1][lr] = b0.y; Bs[nxt][lk + 2][lr] = b0.z; Bs[nxt][lk + 3][lr] = b0.w;
      Bs[nxt][lk + 4][lr] = b1.x; Bs[nxt][lk + 5][lr] = b1.y; Bs[nxt][lk + 6][lr] = b1.z; Bs[nxt][lk + 7][lr] = b1.w;
    }
    __syncthreads();
  }

#pragma unroll
  for (int i = 0; i < 8; ++i) {
    int r = row0 + ty * 8 + i;
    if (r < M) {
#pragma unroll
      for (int j = 0; j < 8; ++j) {
        int c = col0 + tx * 8 + j;
        C[(size_t)r * N + c] = acc[i][j] + bias[c];
      }
    }
  }
}

// ============================ BiLSTM recurrence: PERSISTENT cooperative kernel ============================
// ROUND 6: back to r4's 256-block / 6-unit tile (r5's 512-block split regressed: 2x79KB
// didn't fit 160KB LDS/CU). Persistent kernel runs all Cc steps in ONE launch:
//  - w_hh rows staged to LDS ONCE per launch (was per step).
//  - cross-XCD h exchange via agent-scope atomics (sc0 sc1 -> coherence point/L3),
//    which avoids the full L2 writeback/invalidate that kernel boundaries and
//    grid.sync() pay (~10us and ~30us per step respectively).
//  - grid barrier: __syncthreads (per-wave vmcnt drain = release) + one atomicAdd
//    per block on an L3 counter + tid0 spin on relaxed agent loads; monotonic
//    epoch target (counter zeroed once in first_idx_kernel, never reset).
//  - c stays in a register across all steps of the launch (cbuf only at chunk bounds).
// FMA tile/order identical to round 4 -> bit-exact outputs.
// Cooperative launch guarantees co-residency: 256 blocks x ~122KB LDS = 1 block/CU.
__global__ __launch_bounds__(256) void lstm_persist_kernel(
    const float* __restrict__ pre_f, const float* __restrict__ pre_r,
    const float* __restrict__ whh_f, const float* __restrict__ whh_r,
    float* __restrict__ out, float* __restrict__ hbuf, float* __restrict__ cbuf,
    unsigned int* __restrict__ counter, int s0, int Cc, int ep0) {
  const int wg = blockIdx.x;
  const int dir = wg >> 7;
  const int lw = wg & 127;
  const float* __restrict__ pre = dir ? pre_r : pre_f;
  const float* __restrict__ whh = dir ? whh_r : whh_f;
  float* hb = hbuf + (size_t)dir * 2 * B_ * H_;
  float* cb = cbuf + (size_t)dir * B_ * H_;
  const int tid = threadIdx.x;
  const int u0 = lw * 6;

  const int rgrp = tid >> 6;       // wave index == gate 0..3
  const int lane = tid & 63;
  const int kgrp = lane >> 3;      // 0..7 : k-split
  const int bgrp = lane & 7;       // 0..7 : batch quad

  __shared__ float w_lds[24 * 860];   // 82560 B, skewed: this block's 24 gate rows
  __shared__ float h_lds[32 * 284];   // 36352 B, skewed, one 256-k chunk
  __shared__ float g_lds[32][24];

  // ---- stage 24 weight rows into skewed LDS ONCE (4608 float4, 18/thread) ----
#pragma unroll
  for (int v = 0; v < 18; ++v) {
    int i = v * 256 + tid;          // 0..4607
    int r24 = i / 192;              // 0..23
    int f4 = i - r24 * 192;         // 0..191
    int k = f4 * 4;
    int grow = (r24 / 6) * H_ + u0 + (r24 % 6);
    *(float4*)&w_lds[r24 * 860 + k + 4 * (k >> 5)] =
        *(const float4*)(whh + (size_t)grow * H_ + k);
  }

  // combine-thread ownership: tid<192 owns (batch cb_, unit cui); c kept in register
  const int cui = tid >> 5;        // 0..5 valid when tid < 192
  const int cb_ = tid & 31;
  float creg = 0.0f;
  if (tid < 192 && s0 > 0) creg = cb[(size_t)cb_ * H_ + u0 + cui];

  const int kl0 = kgrp * 32;

  for (int sl = 0; sl < Cc; ++sl) {
    const int s = s0 + sl;
    const int w = dir ? (W_ - 1 - s) : s;
    const int prow = dir ? (Cc - 1 - sl) : sl;

    // pre loads issued early; consumed only in the combine phase
    float pre_g0 = 0.f, pre_g1 = 0.f, pre_g2 = 0.f, pre_g3 = 0.f;
    if (tid < 192) {
      const float* pbt = pre + ((size_t)prow * B_ + cb_) * G_;
      pre_g0 = pbt[0 * H_ + u0 + cui];
      pre_g1 = pbt[1 * H_ + u0 + cui];
      pre_g2 = pbt[2 * H_ + u0 + cui];
      pre_g3 = pbt[3 * H_ + u0 + cui];
    }

    float acc[6][4];
#pragma unroll
    for (int r = 0; r < 6; ++r)
#pragma unroll
      for (int j = 0; j < 4; ++j) acc[r][j] = 0.0f;

    if (s > 0) {
      const float* __restrict__ hprev = hb + (size_t)(s & 1) * B_ * H_;
      for (int kc = 0; kc < H_; kc += 256) {
        __syncthreads();   // previous chunk (or previous step) consumed
        // stage one 256-k chunk of h via agent-scope loads (coherence point, never stale)
#pragma unroll
        for (int v = 0; v < 8; ++v) {
          int e = v * 1024 + tid * 4;
          int bb = e >> 8;
          int kk = e & 255;
          const float* src = hprev + (size_t)bb * H_ + kc + kk;
          float x0 = __hip_atomic_load((const float*)(src + 0), __ATOMIC_RELAXED, __HIP_MEMORY_SCOPE_AGENT);
          float x1 = __hip_atomic_load((const float*)(src + 1), __ATOMIC_RELAXED, __HIP_MEMORY_SCOPE_AGENT);
          float x2 = __hip_atomic_load((const float*)(src + 2), __ATOMIC_RELAXED, __HIP_MEMORY_SCOPE_AGENT);
          float x3 = __hip_atomic_load((const float*)(src + 3), __ATOMIC_RELAXED, __HIP_MEMORY_SCOPE_AGENT);
          int off = bb * 284 + kk + 4 * (kk >> 5);
          h_lds[off + 0] = x0; h_lds[off + 1] = x1; h_lds[off + 2] = x2; h_lds[off + 3] = x3;
        }
        __syncthreads();   // staging visible

        const int wbase = kc + kl0;
#pragma unroll 4
        for (int t = 0; t < 8; ++t) {
          const int kl = kl0 + t * 4;
          const int ka = wbase + t * 4;
          const int hoff = kl + 4 * (kl >> 5);
          const int woff = ka + 4 * (ka >> 5);
          float4 h4_0 = *(const float4*)&h_lds[(4 * bgrp + 0) * 284 + hoff];
          float4 h4_1 = *(const float4*)&h_lds[(4 * bgrp + 1) * 284 + hoff];
          float4 h4_2 = *(const float4*)&h_lds[(4 * bgrp + 2) * 284 + hoff];
          float4 h4_3 = *(const float4*)&h_lds[(4 * bgrp + 3) * 284 + hoff];
#pragma unroll
          for (int r = 0; r < 6; ++r) {
            float4 w4 = *(const float4*)&w_lds[(rgrp * 6 + r) * 860 + woff];
            acc[r][0] += h4_0.x * w4.x + h4_0.y * w4.y + h4_0.z * w4.z + h4_0.w * w4.w;
            acc[r][1] += h4_1.x * w4.x + h4_1.y * w4.y + h4_1.z * w4.z + h4_1.w * w4.w;
            acc[r][2] += h4_2.x * w4.x + h4_2.y * w4.y + h4_2.z * w4.z + h4_2.w * w4.w;
            acc[r][3] += h4_3.x * w4.x + h4_3.y * w4.y + h4_3.z * w4.z + h4_3.w * w4.w;
          }
        }
      }

      // ---- reduce the 8-way k-split across kgrp lanes ----
#pragma unroll
      for (int r = 0; r < 6; ++r)
#pragma unroll
        for (int j = 0; j < 4; ++j) {
          float a = acc[r][j];
          a += __shfl_xor(a, 8, 64);
          a += __shfl_xor(a, 16, 64);
          a += __shfl_xor(a, 32, 64);
          acc[r][j] = a;
        }
      if (kgrp == 0) {
#pragma unroll
        for (int r = 0; r < 6; ++r)
#pragma unroll
          for (int j = 0; j < 4; ++j)
            g_lds[4 * bgrp + j][rgrp * 6 + r] = acc[r][j];
      }
    }

    __syncthreads();

    // ---- gate combine ----
    if (tid < 192) {
      float gi = pre_g0, gf = pre_g1, gg = pre_g2, go = pre_g3;
      if (s > 0) {
        gi += g_lds[cb_][cui];
        gf += g_lds[cb_][6 + cui];
        gg += g_lds[cb_][12 + cui];
        go += g_lds[cb_][18 + cui];
      }
      const float si = 1.0f / (1.0f + expf(-gi));
      const float sf = 1.0f / (1.0f + expf(-gf));
      const float so = 1.0f / (1.0f + expf(-go));
      creg = sf * creg + si * tanhf(gg);
      const float h = so * tanhf(creg);
      float* __restrict__ hnext = hb + (size_t)((s + 1) & 1) * B_ * H_;
      __hip_atomic_store(&hnext[(size_t)cb_ * H_ + u0 + cui], h,
                         __ATOMIC_RELAXED, __HIP_MEMORY_SCOPE_AGENT);
      out[((size_t)w * B_ + cb_) * (2 * H_) + (size_t)dir * H_ + u0 + cui] = h;
    }

    // ---- grid barrier: release = per-wave vmcnt drain in __syncthreads;
    //      signal/wait on an L3 counter; h reads above are agent-scope so no
    //      L2 invalidate is needed on the acquire side. ----
    __syncthreads();
    if (tid == 0) {
      __hip_atomic_fetch_add(counter, 1u, __ATOMIC_RELAXED, __HIP_MEMORY_SCOPE_AGENT);
      const unsigned int tgt = 256u * (unsigned int)(ep0 + sl + 1);
      while (__hip_atomic_load(counter, __ATOMIC_RELAXED, __HIP_MEMORY_SCOPE_AGENT) < tgt) {
        __builtin_amdgcn_s_sleep(2);
      }
    }
    __syncthreads();
  }

  if (tid < 192) cb[(size_t)cb_ * H_ + u0 + cui] = creg;
}

// ============================ logits + softmax ============================
// h2 is [W][B][2H]; prob is [B][W][NT]
__global__ void logits_softmax_kernel(const float* __restrict__ h2, const float* __restrict__ w_lin,
                                      const float* __restrict__ b_lin, float* __restrict__ prob) {
  int i = blockIdx.x * blockDim.x + threadIdx.x;
  if (i >= B_ * W_) return;
  int b = i / W_, w = i % W_;
  const float4* x = (const float4*)(h2 + ((size_t)w * B_ + b) * (2 * H_));
  const float4* w0 = (const float4*)(w_lin);
  const float4* w1 = (const float4*)(w_lin + 2 * H_);
  float l0 = 0.f, l1 = 0.f;
#pragma unroll 4
  for (int k = 0; k < (2 * H_) / 4; ++k) {
    float4 xv = x[k];
    float4 a = w0[k];
    float4 c = w1[k];
    l0 += xv.x * a.x + xv.y * a.y + xv.z * a.z + xv.w * a.w;
    l1 += xv.x * c.x + xv.y * c.y + xv.z * c.z + xv.w * c.w;
  }
  l0 += b_lin[0];
  l1 += b_lin[1];
  float m = fmaxf(l0, l1);
  float e0 = expf(l0 - m), e1 = expf(l1 - m);
  float s = e0 + e1;
  prob[2 * (size_t)i] = e0 / s;
  prob[2 * (size_t)i + 1] = e1 / s;
}

// ============================ CRF ============================
__device__ __forceinline__ float lse2(float a, float b) {
  float m = fmaxf(a, b);
  return m + logf(expf(a - m) + expf(b - m));
}

__global__ void crf_llh_kernel(const float* __restrict__ emis, const int* __restrict__ tags,
                               const float* __restrict__ start, const float* __restrict__ endv,
                               const float* __restrict__ trans, float* __restrict__ loss_out) {
  int tid = threadIdx.x;  // 64 threads
  float val = 0.f;
  if (tid < B_) {
    const float* e = emis + (size_t)tid * W_ * NT_;
    const int* tg = tags + (size_t)tid * W_;
    const float t00 = trans[0], t01 = trans[1], t10 = trans[2], t11 = trans[3];
    int tp = tg[0];
    float num = start[tp] + e[tp];
    float a0 = start[0] + e[0];
    float a1 = start[1] + e[1];
    for (int s = 1; s < W_; ++s) {
      int ts = tg[s];
      num += e[2 * s + ts] + trans[tp * 2 + ts];
      tp = ts;
      float n0 = lse2(a0 + t00, a1 + t10) + e[2 * s];
      float n1 = lse2(a0 + t01, a1 + t11) + e[2 * s + 1];
      a0 = n0;
      a1 = n1;
    }
    num += endv[tp];
    float logZ = lse2(a0 + endv[0], a1 + endv[1]);
    val = num - logZ;
  }
  for (int off = 32; off > 0; off >>= 1) val += __shfl_down(val, off, 64);
  if (tid == 0) loss_out[0] = -(val / (float)B_);
}

__global__ void crf_decode_kernel(const float* __restrict__ emis,
                                  const float* __restrict__ start, const float* __restrict__ endv,
                                  const float* __restrict__ trans, float* __restrict__ path_out) {
  int b = blockIdx.x * blockDim.x + threadIdx.x;
  if (b >= B_) return;
  const float* e = emis + (size_t)b * W_ * NT_;
  const float t00 = trans[0], t01 = trans[1], t10 = trans[2], t11 = trans[3];
  float s0 = start[0] + e[0];
  float s1 = start[1] + e[1];
  unsigned long long bp0[4] = {0ull, 0ull, 0ull, 0ull};
  unsigned long long bp1[4] = {0ull, 0ull, 0ull, 0ull};
  for (int s = 1; s < W_; ++s) {
    float c00 = s0 + t00, c10 = s1 + t10;  // into j=0
    float c01 = s0 + t01, c11 = s1 + t11;  // into j=1
    int b0 = (c10 > c00) ? 1 : 0;          // argmax: first wins ties
    int b1 = (c11 > c01) ? 1 : 0;
    float m0 = b0 ? c10 : c00;
    float m1 = b1 ? c11 : c01;
    int idx = s - 1;
    bp0[idx >> 6] |= ((unsigned long long)b0) << (idx & 63);
    bp1[idx >> 6] |= ((unsigned long long)b1) << (idx & 63);
    s0 = m0 + e[2 * s];
    s1 = m1 + e[2 * s + 1];
  }
  int tag = ((s1 + endv[1]) > (s0 + endv[0])) ? 1 : 0;
  path_out[(size_t)b * W_ + (W_ - 1)] = (float)tag;
  for (int s = W_ - 2; s >= 0; --s) {
    unsigned long long word = tag ? bp1[s >> 6] : bp0[s >> 6];
    tag = (int)((word >> (s & 63)) & 1ull);
    path_out[(size_t)b * W_ + s] = (float)tag;
  }
}

// ============================ launch ============================
extern "C" void kernel_launch(void* const* d_in, const int* in_sizes, int n_in,
                              void* d_out, int out_size, void* d_ws, size_t ws_size,
                              hipStream_t stream) {
  const float* bert_out = (const float*)d_in[0];
  const int* words_ids = (const int*)d_in[1];
  const int* label_detect = (const int*)d_in[2];
  const float* w_ih_l0 = (const float*)d_in[3];
  const float* w_hh_l0 = (const float*)d_in[4];
  const float* b_l0 = (const float*)d_in[5];
  const float* w_ih_l0r = (const float*)d_in[6];
  const float* w_hh_l0r = (const float*)d_in[7];
  const float* b_l0r = (const float*)d_in[8];
  const float* w_ih_l1 = (const float*)d_in[9];
  const float* w_hh_l1 = (const float*)d_in[10];
  const float* b_l1 = (const float*)d_in[11];
  const float* w_ih_l1r = (const float*)d_in[12];
  const float* w_hh_l1r = (const float*)d_in[13];
  const float* b_l1r = (const float*)d_in[14];
  const float* w_lin = (const float*)d_in[15];
  const float* b_lin = (const float*)d_in[16];
  const float* crf_start = (const float*)d_in[17];
  const float* crf_end = (const float*)d_in[18];
  const float* crf_trans = (const float*)d_in[19];

  float* out = (float*)d_out;
  float* path_out = out;               // 8000
  float* prob_out = out + B_ * W_;     // 16000
  float* loss_out = out + B_ * W_ * 3; // 1

  // Adaptive time-chunk size: largest C (divides 250) whose workspace fits ws_size.
  auto need = [](int c) -> size_t { return 4ull * (24731520ull + 196608ull * (size_t)c); };
  int C = 10;
  if (ws_size >= need(250)) C = 250;
  else if (ws_size >= need(125)) C = 125;
  else if (ws_size >= need(50)) C = 50;
  else if (ws_size >= need(25)) C = 25;
  const int nchunk = W_ / C;
  const size_t CBG = (size_t)C * B_ * G_;

  // workspace layout (floats):
  //   [0 .. 12.288M)         h2 region  (feat [W][B][D] aliases its first 6.144M floats)
  //   [12.288M .. 24.576M)   h1 [W][B][2H]
  //   then preA chunk, preB chunk, hbuf, cbuf, fidx, barrier counter
  float* h2 = (float*)d_ws;
  float* feat = h2;  // alias: feat dead before h2 is written
  float* h1 = h2 + 12288000;
  float* preA = h1 + 12288000;
  float* preB = preA + CBG;
  float* hbuf = preB + CBG;
  float* cbuf = hbuf + 2 * 2 * B_ * H_;
  int* fidx = (int*)(cbuf + 2 * B_ * H_);
  unsigned int* counter = (unsigned int*)(fidx + B_ * W_);

  // 1) first-subtoken gather -> feat [W][B][D]  (also zeroes the barrier counter)
  first_idx_kernel<<<(B_ * W_ + 255) / 256, 256, 0, stream>>>(words_ids, fidx, counter);
  gather_kernel<<<(B_ * W_ * (D_ / 4) + 255) / 256, 256, 0, stream>>>(bert_out, fidx, feat);

  const int Mc = C * B_;
  dim3 ggrid((Mc + 127) / 128, G_ / 128);
  int ep = 0;  // barrier epoch base (monotonic across all persistent launches)

  // 2) layer 0: per chunk, fwd+rev input projections then one persistent recurrence launch
  for (int ch = 0; ch < nchunk; ++ch) {
    const int s0 = ch * C;
    gemm_bias_kernel<<<ggrid, 256, 0, stream>>>(feat + (size_t)s0 * B_ * D_, w_ih_l0, b_l0, preA, Mc, G_, D_);
    gemm_bias_kernel<<<ggrid, 256, 0, stream>>>(feat + (size_t)(W_ - C - s0) * B_ * D_, w_ih_l0r, b_l0r, preB, Mc, G_, D_);
    const float* a0 = preA; const float* a1 = preB;
    const float* a2 = w_hh_l0; const float* a3 = w_hh_l0r;
    float* a4 = h1; float* a5 = hbuf; float* a6 = cbuf;
    unsigned int* a7 = counter; int a8 = s0; int a9 = C; int a10 = ep;
    void* args[] = {&a0, &a1, &a2, &a3, &a4, &a5, &a6, &a7, &a8, &a9, &a10};
    hipLaunchCooperativeKernel((void*)lstm_persist_kernel, dim3(256), dim3(256), args, 0, stream);
    ep += C;
  }

  // 3) layer 1 (K = 1536)
  for (int ch = 0; ch < nchunk; ++ch) {
    const int s0 = ch * C;
    gemm_bias_kernel<<<ggrid, 256, 0, stream>>>(h1 + (size_t)s0 * B_ * (2 * H_), w_ih_l1, b_l1, preA, Mc, G_, 2 * H_);
    gemm_bias_kernel<<<ggrid, 256, 0, stream>>>(h1 + (size_t)(W_ - C - s0) * B_ * (2 * H_), w_ih_l1r, b_l1r, preB, Mc, G_, 2 * H_);
    const float* a0 = preA; const float* a1 = preB;
    const float* a2 = w_hh_l1; const float* a3 = w_hh_l1r;
    float* a4 = h2; float* a5 = hbuf; float* a6 = cbuf;
    unsigned int* a7 = counter; int a8 = s0; int a9 = C; int a10 = ep;
    void* args[] = {&a0, &a1, &a2, &a3, &a4, &a5, &a6, &a7, &a8, &a9, &a10};
    hipLaunchCooperativeKernel((void*)lstm_persist_kernel, dim3(256), dim3(256), args, 0, stream);
    ep += C;
  }

  // 4) logits + softmax -> ner_prob (written straight into d_out)
  logits_softmax_kernel<<<(B_ * W_ + 255) / 256, 256, 0, stream>>>(h2, w_lin, b_lin, prob_out);

  // 5) CRF log-likelihood -> loss, Viterbi decode -> path
  crf_llh_kernel<<<1, 64, 0, stream>>>(prob_out, label_detect, crf_start, crf_end, crf_trans, loss_out);
  crf_decode_kernel<<<1, 64, 0, stream>>>(prob_out, crf_start, crf_end, crf_trans, path_out);
}

// Round 7
// 12959.737 us; speedup vs baseline: 1.3417x; 1.3417x over previous
//
#include <hip/hip_runtime.h>
#include <cmath>

#define B_ 32
#define T_ 512
#define W_ 250
#define D_ 768
#define H_ 768
#define G_ 3072   // 4*H
#define NT_ 2

#define NBAR_ 1152   // barrier area: 8 grp lines (64 uints apart) + root line + 8 go lines

// ============================ first-subtoken gather ============================
__global__ void first_idx_kernel(const int* __restrict__ words_ids, int* __restrict__ fidx,
                                 unsigned int* __restrict__ counter) {
  int i = blockIdx.x * blockDim.x + threadIdx.x;
  if (i < NBAR_) counter[i] = 0u;  // zero the whole barrier area
  if (i >= B_ * W_) return;
  int b = i / W_, w = i % W_;
  const int* row = words_ids + (size_t)b * T_;
  int idx = T_ - 1;
  for (int t = 0; t < T_; ++t) {
    if (row[t] == w) { idx = t; break; }
  }
  fidx[i] = idx;
}

// feat layout: [W][B][D]  (time-major so a time-chunk is contiguous GEMM rows)
__global__ void gather_kernel(const float* __restrict__ bert_out, const int* __restrict__ fidx,
                              float* __restrict__ feat) {
  int i = blockIdx.x * blockDim.x + threadIdx.x;
  const int nv = D_ / 4;
  if (i >= B_ * W_ * nv) return;
  int bw = i / nv, d4 = i % nv;
  int b = bw / W_, w = bw % W_;
  int t = fidx[bw];
  float4 v = ((const float4*)(bert_out + ((size_t)b * T_ + t) * D_))[d4];
  ((float4*)(feat + ((size_t)w * B_ + b) * D_))[d4] = v;
}

// ============================ fp32 GEMM: C[M,N] = A[M,K] * B[N,K]^T + bias[N] ============================
__global__ __launch_bounds__(256) void gemm_bias_kernel(
    const float* __restrict__ A, const float* __restrict__ Bm,
    const float* __restrict__ bias, float* __restrict__ C,
    int M, int N, int K) {
  __shared__ float As[2][16][132];
  __shared__ float Bs[2][16][132];
  const int tid = threadIdx.x;
  const int row0 = blockIdx.x * 128;
  const int col0 = blockIdx.y * 128;
  const int tx = tid & 15;       // N dim of microtile
  const int ty = tid >> 4;       // M dim of microtile
  const int lr = tid >> 1;       // 0..127 : tile row this thread loads
  const int lk = (tid & 1) * 8;  // k offset 0 or 8

  int ar = row0 + lr;
  if (ar >= M) ar = M - 1;                 // clamp (results of padded rows never stored)
  const float* __restrict__ Ap = A + (size_t)ar * K + lk;
  const float* __restrict__ Bp = Bm + (size_t)(col0 + lr) * K + lk;

  float acc[8][8];
#pragma unroll
  for (int i = 0; i < 8; ++i)
#pragma unroll
    for (int j = 0; j < 8; ++j) acc[i][j] = 0.0f;

  const int nk = K >> 4;

  {
    float4 a0 = *(const float4*)(Ap + 0);
    float4 a1 = *(const float4*)(Ap + 4);
    float4 b0 = *(const float4*)(Bp + 0);
    float4 b1 = *(const float4*)(Bp + 4);
    As[0][lk + 0][lr] = a0.x; As[0][lk + 1][lr] = a0.y; As[0][lk + 2][lr] = a0.z; As[0][lk + 3][lr] = a0.w;
    As[0][lk + 4][lr] = a1.x; As[0][lk + 5][lr] = a1.y; As[0][lk + 6][lr] = a1.z; As[0][lk + 7][lr] = a1.w;
    Bs[0][lk + 0][lr] = b0.x; Bs[0][lk + 1][lr] = b0.y; Bs[0][lk + 2][lr] = b0.z; Bs[0][lk + 3][lr] = b0.w;
    Bs[0][lk + 4][lr] = b1.x; Bs[0][lk + 5][lr] = b1.y; Bs[0][lk + 6][lr] = b1.z; Bs[0][lk + 7][lr] = b1.w;
  }
  __syncthreads();

  for (int t = 0; t < nk; ++t) {
    const int cur = t & 1;
    float4 a0, a1, b0, b1;
    const bool pf = (t + 1 < nk);
    if (pf) {
      const int k0 = (t + 1) << 4;
      a0 = *(const float4*)(Ap + k0);
      a1 = *(const float4*)(Ap + k0 + 4);
      b0 = *(const float4*)(Bp + k0);
      b1 = *(const float4*)(Bp + k0 + 4);
    }
#pragma unroll
    for (int k = 0; k < 16; ++k) {
      float a[8], b[8];
      *(float4*)&a[0] = *(const float4*)&As[cur][k][ty * 8];
      *(float4*)&a[4] = *(const float4*)&As[cur][k][ty * 8 + 4];
      *(float4*)&b[0] = *(const float4*)&Bs[cur][k][tx * 8];
      *(float4*)&b[4] = *(const float4*)&Bs[cur][k][tx * 8 + 4];
#pragma unroll
      for (int i = 0; i < 8; ++i)
#pragma unroll
        for (int j = 0; j < 8; ++j) acc[i][j] += a[i] * b[j];
    }
    if (pf) {
      const int nxt = cur ^ 1;
      As[nxt][lk + 0][lr] = a0.x; As[nxt][lk + 1][lr] = a0.y; As[nxt][lk + 2][lr] = a0.z; As[nxt][lk + 3][lr] = a0.w;
      As[nxt][lk + 4][lr] = a1.x; As[nxt][lk + 5][lr] = a1.y; As[nxt][lk + 6][lr] = a1.z; As[nxt][lk + 7][lr] = a1.w;
      Bs[nxt][lk + 0][lr] = b0.x; Bs[nxt][lk + 1][lr] = b0.y; Bs[nxt][lk + 2][lr] = b0.z; Bs[nxt][lk + 3][lr] = b0.w;
      Bs[nxt][lk + 4][lr] = b1.x; Bs[nxt][lk + 5][lr] = b1.y; Bs[nxt][lk + 6][lr] = b1.z; Bs[nxt][lk + 7][lr] = b1.w;
    }
    __syncthreads();
  }

#pragma unroll
  for (int i = 0; i < 8; ++i) {
    int r = row0 + ty * 8 + i;
    if (r < M) {
#pragma unroll
      for (int j = 0; j < 8; ++j) {
        int c = col0 + tx * 8 + j;
        C[(size_t)r * N + c] = acc[i][j] + bias[c];
      }
    }
  }
}

// ============================ BiLSTM recurrence: PERSISTENT cooperative kernel ============================
// ROUND 7: r6 structure with its two measured mistakes fixed.
//  FIX 1 (barrier): two-level. 8 group counters on 256B-separated lines (wg&7), each
//    line sees <=32 arrivals + <=31 pollers; 8 group leaders arrive at a root line;
//    leaders poll root then release a per-group "go" word. Cumulative (monotonic)
//    counts; epochs phased: group-g arrivals for epoch e+1 cannot begin until go[g]=e,
//    which requires root=8e, which requires all 256 arrivals of epoch e.
//  FIX 2 (h exchange): 8-byte agent-scope atomic loads (global_load_dwordx2 sc0 sc1)
//    instead of 4-byte scalars - same bytes to same h_lds slots, half the instructions.
// Everything else identical to r6 (w staged once, c in register, r4 FMA order) -> bit-exact.
__global__ __launch_bounds__(256) void lstm_persist_kernel(
    const float* __restrict__ pre_f, const float* __restrict__ pre_r,
    const float* __restrict__ whh_f, const float* __restrict__ whh_r,
    float* __restrict__ out, float* __restrict__ hbuf, float* __restrict__ cbuf,
    unsigned int* __restrict__ counter, int s0, int Cc, int ep0) {
  const int wg = blockIdx.x;
  const int dir = wg >> 7;
  const int lw = wg & 127;
  const float* __restrict__ pre = dir ? pre_r : pre_f;
  const float* __restrict__ whh = dir ? whh_r : whh_f;
  float* hb = hbuf + (size_t)dir * 2 * B_ * H_;
  float* cb = cbuf + (size_t)dir * B_ * H_;
  const int tid = threadIdx.x;
  const int u0 = lw * 6;

  const int rgrp = tid >> 6;       // wave index == gate 0..3
  const int lane = tid & 63;
  const int kgrp = lane >> 3;      // 0..7 : k-split
  const int bgrp = lane & 7;       // 0..7 : batch quad

  __shared__ float w_lds[24 * 860];   // 82560 B, skewed: this block's 24 gate rows
  __shared__ float h_lds[32 * 284];   // 36352 B, skewed, one 256-k chunk
  __shared__ float g_lds[32][24];

  // barrier lines for this block
  unsigned int* __restrict__ grp  = counter + ((wg & 7) << 6);        // 8 lines, 256B apart
  unsigned int* __restrict__ root = counter + 512;
  unsigned int* __restrict__ gow  = counter + 576 + ((wg & 7) << 6);  // 8 go lines

  // ---- stage 24 weight rows into skewed LDS ONCE (4608 float4, 18/thread) ----
#pragma unroll
  for (int v = 0; v < 18; ++v) {
    int i = v * 256 + tid;          // 0..4607
    int r24 = i / 192;              // 0..23
    int f4 = i - r24 * 192;         // 0..191
    int k = f4 * 4;
    int grow = (r24 / 6) * H_ + u0 + (r24 % 6);
    *(float4*)&w_lds[r24 * 860 + k + 4 * (k >> 5)] =
        *(const float4*)(whh + (size_t)grow * H_ + k);
  }

  // combine-thread ownership: tid<192 owns (batch cb_, unit cui); c kept in register
  const int cui = tid >> 5;        // 0..5 valid when tid < 192
  const int cb_ = tid & 31;
  float creg = 0.0f;
  if (tid < 192 && s0 > 0) creg = cb[(size_t)cb_ * H_ + u0 + cui];

  const int kl0 = kgrp * 32;

  for (int sl = 0; sl < Cc; ++sl) {
    const int s = s0 + sl;
    const int w = dir ? (W_ - 1 - s) : s;
    const int prow = dir ? (Cc - 1 - sl) : sl;

    // pre loads issued early; consumed only in the combine phase
    float pre_g0 = 0.f, pre_g1 = 0.f, pre_g2 = 0.f, pre_g3 = 0.f;
    if (tid < 192) {
      const float* pbt = pre + ((size_t)prow * B_ + cb_) * G_;
      pre_g0 = pbt[0 * H_ + u0 + cui];
      pre_g1 = pbt[1 * H_ + u0 + cui];
      pre_g2 = pbt[2 * H_ + u0 + cui];
      pre_g3 = pbt[3 * H_ + u0 + cui];
    }

    float acc[6][4];
#pragma unroll
    for (int r = 0; r < 6; ++r)
#pragma unroll
      for (int j = 0; j < 4; ++j) acc[r][j] = 0.0f;

    if (s > 0) {
      const float* __restrict__ hprev = hb + (size_t)(s & 1) * B_ * H_;
      for (int kc = 0; kc < H_; kc += 256) {
        __syncthreads();   // previous chunk (or previous step) consumed
        // stage one 256-k chunk of h via 8-byte agent-scope loads (coherence point)
#pragma unroll
        for (int v = 0; v < 8; ++v) {
          int e = v * 1024 + tid * 4;
          int bb = e >> 8;
          int kk = e & 255;
          const unsigned long long* src =
              (const unsigned long long*)(hprev + (size_t)bb * H_ + kc + kk);
          union { unsigned long long u; float f[2]; } q0, q1;
          q0.u = __hip_atomic_load(src + 0, __ATOMIC_RELAXED, __HIP_MEMORY_SCOPE_AGENT);
          q1.u = __hip_atomic_load(src + 1, __ATOMIC_RELAXED, __HIP_MEMORY_SCOPE_AGENT);
          int off = bb * 284 + kk + 4 * (kk >> 5);
          h_lds[off + 0] = q0.f[0]; h_lds[off + 1] = q0.f[1];
          h_lds[off + 2] = q1.f[0]; h_lds[off + 3] = q1.f[1];
        }
        __syncthreads();   // staging visible

        const int wbase = kc + kl0;
#pragma unroll 4
        for (int t = 0; t < 8; ++t) {
          const int kl = kl0 + t * 4;
          const int ka = wbase + t * 4;
          const int hoff = kl + 4 * (kl >> 5);
          const int woff = ka + 4 * (ka >> 5);
          float4 h4_0 = *(const float4*)&h_lds[(4 * bgrp + 0) * 284 + hoff];
          float4 h4_1 = *(const float4*)&h_lds[(4 * bgrp + 1) * 284 + hoff];
          float4 h4_2 = *(const float4*)&h_lds[(4 * bgrp + 2) * 284 + hoff];
          float4 h4_3 = *(const float4*)&h_lds[(4 * bgrp + 3) * 284 + hoff];
#pragma unroll
          for (int r = 0; r < 6; ++r) {
            float4 w4 = *(const float4*)&w_lds[(rgrp * 6 + r) * 860 + woff];
            acc[r][0] += h4_0.x * w4.x + h4_0.y * w4.y + h4_0.z * w4.z + h4_0.w * w4.w;
            acc[r][1] += h4_1.x * w4.x + h4_1.y * w4.y + h4_1.z * w4.z + h4_1.w * w4.w;
            acc[r][2] += h4_2.x * w4.x + h4_2.y * w4.y + h4_2.z * w4.z + h4_2.w * w4.w;
            acc[r][3] += h4_3.x * w4.x + h4_3.y * w4.y + h4_3.z * w4.z + h4_3.w * w4.w;
          }
        }
      }

      // ---- reduce the 8-way k-split across kgrp lanes ----
#pragma unroll
      for (int r = 0; r < 6; ++r)
#pragma unroll
        for (int j = 0; j < 4; ++j) {
          float a = acc[r][j];
          a += __shfl_xor(a, 8, 64);
          a += __shfl_xor(a, 16, 64);
          a += __shfl_xor(a, 32, 64);
          acc[r][j] = a;
        }
      if (kgrp == 0) {
#pragma unroll
        for (int r = 0; r < 6; ++r)
#pragma unroll
          for (int j = 0; j < 4; ++j)
            g_lds[4 * bgrp + j][rgrp * 6 + r] = acc[r][j];
      }
    }

    __syncthreads();

    // ---- gate combine ----
    if (tid < 192) {
      float gi = pre_g0, gf = pre_g1, gg = pre_g2, go = pre_g3;
      if (s > 0) {
        gi += g_lds[cb_][cui];
        gf += g_lds[cb_][6 + cui];
        gg += g_lds[cb_][12 + cui];
        go += g_lds[cb_][18 + cui];
      }
      const float si = 1.0f / (1.0f + expf(-gi));
      const float sf = 1.0f / (1.0f + expf(-gf));
      const float so = 1.0f / (1.0f + expf(-go));
      creg = sf * creg + si * tanhf(gg);
      const float h = so * tanhf(creg);
      float* __restrict__ hnext = hb + (size_t)((s + 1) & 1) * B_ * H_;
      __hip_atomic_store(&hnext[(size_t)cb_ * H_ + u0 + cui], h,
                         __ATOMIC_RELAXED, __HIP_MEMORY_SCOPE_AGENT);
      out[((size_t)w * B_ + cb_) * (2 * H_) + (size_t)dir * H_ + u0 + cui] = h;
    }

    // ---- two-level grid barrier (cumulative epochs, 256B-separated lines) ----
    __syncthreads();   // drains vmcnt: h stores are at the coherence point
    if (tid == 0) {
      const unsigned int ep1 = (unsigned int)(ep0 + sl + 1);
      unsigned int old = __hip_atomic_fetch_add(grp, 1u, __ATOMIC_RELAXED, __HIP_MEMORY_SCOPE_AGENT);
      if (old == 32u * ep1 - 1u) {
        // group leader: last arrival of this group this epoch
        __hip_atomic_fetch_add(root, 1u, __ATOMIC_RELAXED, __HIP_MEMORY_SCOPE_AGENT);
        while (__hip_atomic_load(root, __ATOMIC_RELAXED, __HIP_MEMORY_SCOPE_AGENT) < 8u * ep1) {
          __builtin_amdgcn_s_sleep(2);
        }
        __hip_atomic_store(gow, ep1, __ATOMIC_RELAXED, __HIP_MEMORY_SCOPE_AGENT);
      } else {
        while (__hip_atomic_load(gow, __ATOMIC_RELAXED, __HIP_MEMORY_SCOPE_AGENT) < ep1) {
          __builtin_amdgcn_s_sleep(2);
        }
      }
    }
    __syncthreads();
  }

  if (tid < 192) cb[(size_t)cb_ * H_ + u0 + cui] = creg;
}

// ============================ logits + softmax ============================
// h2 is [W][B][2H]; prob is [B][W][NT]
__global__ void logits_softmax_kernel(const float* __restrict__ h2, const float* __restrict__ w_lin,
                                      const float* __restrict__ b_lin, float* __restrict__ prob) {
  int i = blockIdx.x * blockDim.x + threadIdx.x;
  if (i >= B_ * W_) return;
  int b = i / W_, w = i % W_;
  const float4* x = (const float4*)(h2 + ((size_t)w * B_ + b) * (2 * H_));
  const float4* w0 = (const float4*)(w_lin);
  const float4* w1 = (const float4*)(w_lin + 2 * H_);
  float l0 = 0.f, l1 = 0.f;
#pragma unroll 4
  for (int k = 0; k < (2 * H_) / 4; ++k) {
    float4 xv = x[k];
    float4 a = w0[k];
    float4 c = w1[k];
    l0 += xv.x * a.x + xv.y * a.y + xv.z * a.z + xv.w * a.w;
    l1 += xv.x * c.x + xv.y * c.y + xv.z * c.z + xv.w * c.w;
  }
  l0 += b_lin[0];
  l1 += b_lin[1];
  float m = fmaxf(l0, l1);
  float e0 = expf(l0 - m), e1 = expf(l1 - m);
  float s = e0 + e1;
  prob[2 * (size_t)i] = e0 / s;
  prob[2 * (size_t)i + 1] = e1 / s;
}

// ============================ CRF ============================
__device__ __forceinline__ float lse2(float a, float b) {
  float m = fmaxf(a, b);
  return m + logf(expf(a - m) + expf(b - m));
}

__global__ void crf_llh_kernel(const float* __restrict__ emis, const int* __restrict__ tags,
                               const float* __restrict__ start, const float* __restrict__ endv,
                               const float* __restrict__ trans, float* __restrict__ loss_out) {
  int tid = threadIdx.x;  // 64 threads
  float val = 0.f;
  if (tid < B_) {
    const float* e = emis + (size_t)tid * W_ * NT_;
    const int* tg = tags + (size_t)tid * W_;
    const float t00 = trans[0], t01 = trans[1], t10 = trans[2], t11 = trans[3];
    int tp = tg[0];
    float num = start[tp] + e[tp];
    float a0 = start[0] + e[0];
    float a1 = start[1] + e[1];
    for (int s = 1; s < W_; ++s) {
      int ts = tg[s];
      num += e[2 * s + ts] + trans[tp * 2 + ts];
      tp = ts;
      float n0 = lse2(a0 + t00, a1 + t10) + e[2 * s];
      float n1 = lse2(a0 + t01, a1 + t11) + e[2 * s + 1];
      a0 = n0;
      a1 = n1;
    }
    num += endv[tp];
    float logZ = lse2(a0 + endv[0], a1 + endv[1]);
    val = num - logZ;
  }
  for (int off = 32; off > 0; off >>= 1) val += __shfl_down(val, off, 64);
  if (tid == 0) loss_out[0] = -(val / (float)B_);
}

__global__ void crf_decode_kernel(const float* __restrict__ emis,
                                  const float* __restrict__ start, const float* __restrict__ endv,
                                  const float* __restrict__ trans, float* __restrict__ path_out) {
  int b = blockIdx.x * blockDim.x + threadIdx.x;
  if (b >= B_) return;
  const float* e = emis + (size_t)b * W_ * NT_;
  const float t00 = trans[0], t01 = trans[1], t10 = trans[2], t11 = trans[3];
  float s0 = start[0] + e[0];
  float s1 = start[1] + e[1];
  unsigned long long bp0[4] = {0ull, 0ull, 0ull, 0ull};
  unsigned long long bp1[4] = {0ull, 0ull, 0ull, 0ull};
  for (int s = 1; s < W_; ++s) {
    float c00 = s0 + t00, c10 = s1 + t10;  // into j=0
    float c01 = s0 + t01, c11 = s1 + t11;  // into j=1
    int b0 = (c10 > c00) ? 1 : 0;          // argmax: first wins ties
    int b1 = (c11 > c01) ? 1 : 0;
    float m0 = b0 ? c10 : c00;
    float m1 = b1 ? c11 : c01;
    int idx = s - 1;
    bp0[idx >> 6] |= ((unsigned long long)b0) << (idx & 63);
    bp1[idx >> 6] |= ((unsigned long long)b1) << (idx & 63);
    s0 = m0 + e[2 * s];
    s1 = m1 + e[2 * s + 1];
  }
  int tag = ((s1 + endv[1]) > (s0 + endv[0])) ? 1 : 0;
  path_out[(size_t)b * W_ + (W_ - 1)] = (float)tag;
  for (int s = W_ - 2; s >= 0; --s) {
    unsigned long long word = tag ? bp1[s >> 6] : bp0[s >> 6];
    tag = (int)((word >> (s & 63)) & 1ull);
    path_out[(size_t)b * W_ + s] = (float)tag;
  }
}

// ============================ launch ============================
extern "C" void kernel_launch(void* const* d_in, const int* in_sizes, int n_in,
                              void* d_out, int out_size, void* d_ws, size_t ws_size,
                              hipStream_t stream) {
  const float* bert_out = (const float*)d_in[0];
  const int* words_ids = (const int*)d_in[1];
  const int* label_detect = (const int*)d_in[2];
  const float* w_ih_l0 = (const float*)d_in[3];
  const float* w_hh_l0 = (const float*)d_in[4];
  const float* b_l0 = (const float*)d_in[5];
  const float* w_ih_l0r = (const float*)d_in[6];
  const float* w_hh_l0r = (const float*)d_in[7];
  const float* b_l0r = (const float*)d_in[8];
  const float* w_ih_l1 = (const float*)d_in[9];
  const float* w_hh_l1 = (const float*)d_in[10];
  const float* b_l1 = (const float*)d_in[11];
  const float* w_ih_l1r = (const float*)d_in[12];
  const float* w_hh_l1r = (const float*)d_in[13];
  const float* b_l1r = (const float*)d_in[14];
  const float* w_lin = (const float*)d_in[15];
  const float* b_lin = (const float*)d_in[16];
  const float* crf_start = (const float*)d_in[17];
  const float* crf_end = (const float*)d_in[18];
  const float* crf_trans = (const float*)d_in[19];

  float* out = (float*)d_out;
  float* path_out = out;               // 8000
  float* prob_out = out + B_ * W_;     // 16000
  float* loss_out = out + B_ * W_ * 3; // 1

  // Adaptive time-chunk size: largest C (divides 250) whose workspace fits ws_size.
  auto need = [](int c) -> size_t { return 4ull * (24732672ull + 196608ull * (size_t)c); };
  int C = 10;
  if (ws_size >= need(250)) C = 250;
  else if (ws_size >= need(125)) C = 125;
  else if (ws_size >= need(50)) C = 50;
  else if (ws_size >= need(25)) C = 25;
  const int nchunk = W_ / C;
  const size_t CBG = (size_t)C * B_ * G_;

  // workspace layout (floats):
  //   [0 .. 12.288M)         h2 region  (feat [W][B][D] aliases its first 6.144M floats)
  //   [12.288M .. 24.576M)   h1 [W][B][2H]
  //   then preA chunk, preB chunk, hbuf, cbuf, fidx, barrier area (NBAR_ uints)
  float* h2 = (float*)d_ws;
  float* feat = h2;  // alias: feat dead before h2 is written
  float* h1 = h2 + 12288000;
  float* preA = h1 + 12288000;
  float* preB = preA + CBG;
  float* hbuf = preB + CBG;
  float* cbuf = hbuf + 2 * 2 * B_ * H_;
  int* fidx = (int*)(cbuf + 2 * B_ * H_);
  unsigned int* counter = (unsigned int*)(fidx + B_ * W_);

  // 1) first-subtoken gather -> feat [W][B][D]  (also zeroes the barrier area)
  first_idx_kernel<<<(B_ * W_ + 255) / 256, 256, 0, stream>>>(words_ids, fidx, counter);
  gather_kernel<<<(B_ * W_ * (D_ / 4) + 255) / 256, 256, 0, stream>>>(bert_out, fidx, feat);

  const int Mc = C * B_;
  dim3 ggrid((Mc + 127) / 128, G_ / 128);
  int ep = 0;  // barrier epoch base (monotonic across all persistent launches)

  // 2) layer 0: per chunk, fwd+rev input projections then one persistent recurrence launch
  for (int ch = 0; ch < nchunk; ++ch) {
    const int s0 = ch * C;
    gemm_bias_kernel<<<ggrid, 256, 0, stream>>>(feat + (size_t)s0 * B_ * D_, w_ih_l0, b_l0, preA, Mc, G_, D_);
    gemm_bias_kernel<<<ggrid, 256, 0, stream>>>(feat + (size_t)(W_ - C - s0) * B_ * D_, w_ih_l0r, b_l0r, preB, Mc, G_, D_);
    const float* a0 = preA; const float* a1 = preB;
    const float* a2 = w_hh_l0; const float* a3 = w_hh_l0r;
    float* a4 = h1; float* a5 = hbuf; float* a6 = cbuf;
    unsigned int* a7 = counter; int a8 = s0; int a9 = C; int a10 = ep;
    void* args[] = {&a0, &a1, &a2, &a3, &a4, &a5, &a6, &a7, &a8, &a9, &a10};
    hipLaunchCooperativeKernel((void*)lstm_persist_kernel, dim3(256), dim3(256), args, 0, stream);
    ep += C;
  }

  // 3) layer 1 (K = 1536)
  for (int ch = 0; ch < nchunk; ++ch) {
    const int s0 = ch * C;
    gemm_bias_kernel<<<ggrid, 256, 0, stream>>>(h1 + (size_t)s0 * B_ * (2 * H_), w_ih_l1, b_l1, preA, Mc, G_, 2 * H_);
    gemm_bias_kernel<<<ggrid, 256, 0, stream>>>(h1 + (size_t)(W_ - C - s0) * B_ * (2 * H_), w_ih_l1r, b_l1r, preB, Mc, G_, 2 * H_);
    const float* a0 = preA; const float* a1 = preB;
    const float* a2 = w_hh_l1; const float* a3 = w_hh_l1r;
    float* a4 = h2; float* a5 = hbuf; float* a6 = cbuf;
    unsigned int* a7 = counter; int a8 = s0; int a9 = C; int a10 = ep;
    void* args[] = {&a0, &a1, &a2, &a3, &a4, &a5, &a6, &a7, &a8, &a9, &a10};
    hipLaunchCooperativeKernel((void*)lstm_persist_kernel, dim3(256), dim3(256), args, 0, stream);
    ep += C;
  }

  // 4) logits + softmax -> ner_prob (written straight into d_out)
  logits_softmax_kernel<<<(B_ * W_ + 255) / 256, 256, 0, stream>>>(h2, w_lin, b_lin, prob_out);

  // 5) CRF log-likelihood -> loss, Viterbi decode -> path
  crf_llh_kernel<<<1, 64, 0, stream>>>(prob_out, label_detect, crf_start, crf_end, crf_trans, loss_out);
  crf_decode_kernel<<<1, 64, 0, stream>>>(prob_out, crf_start, crf_end, crf_trans, path_out);
}

// Round 9
// 10814.893 us; speedup vs baseline: 1.6078x; 1.1983x over previous
//
#include <hip/hip_runtime.h>
#include <cmath>

#define B_ 32
#define T_ 512
#define W_ 250
#define D_ 768
#define H_ 768
#define G_ 3072   // 4*H
#define NT_ 2

#define NBAR_ 1152   // barrier area: 8 grp lines (64 uints apart) + root line + 8 go lines

// ============================ first-subtoken gather ============================
__global__ void first_idx_kernel(const int* __restrict__ words_ids, int* __restrict__ fidx,
                                 unsigned int* __restrict__ counter) {
  int i = blockIdx.x * blockDim.x + threadIdx.x;
  if (i < NBAR_) counter[i] = 0u;  // zero the whole barrier area
  if (i >= B_ * W_) return;
  int b = i / W_, w = i % W_;
  const int* row = words_ids + (size_t)b * T_;
  int idx = T_ - 1;
  for (int t = 0; t < T_; ++t) {
    if (row[t] == w) { idx = t; break; }
  }
  fidx[i] = idx;
}

// feat layout: [W][B][D]  (time-major so a time-chunk is contiguous GEMM rows)
__global__ void gather_kernel(const float* __restrict__ bert_out, const int* __restrict__ fidx,
                              float* __restrict__ feat) {
  int i = blockIdx.x * blockDim.x + threadIdx.x;
  const int nv = D_ / 4;
  if (i >= B_ * W_ * nv) return;
  int bw = i / nv, d4 = i % nv;
  int b = bw / W_, w = bw % W_;
  int t = fidx[bw];
  float4 v = ((const float4*)(bert_out + ((size_t)b * T_ + t) * D_))[d4];
  ((float4*)(feat + ((size_t)w * B_ + b) * D_))[d4] = v;
}

// ============================ fp32 GEMM: C[M,N] = A[M,K] * B[N,K]^T + bias[N] ============================
__global__ __launch_bounds__(256) void gemm_bias_kernel(
    const float* __restrict__ A, const float* __restrict__ Bm,
    const float* __restrict__ bias, float* __restrict__ C,
    int M, int N, int K) {
  __shared__ float As[2][16][132];
  __shared__ float Bs[2][16][132];
  const int tid = threadIdx.x;
  const int row0 = blockIdx.x * 128;
  const int col0 = blockIdx.y * 128;
  const int tx = tid & 15;       // N dim of microtile
  const int ty = tid >> 4;       // M dim of microtile
  const int lr = tid >> 1;       // 0..127 : tile row this thread loads
  const int lk = (tid & 1) * 8;  // k offset 0 or 8

  int ar = row0 + lr;
  if (ar >= M) ar = M - 1;                 // clamp (results of padded rows never stored)
  const float* __restrict__ Ap = A + (size_t)ar * K + lk;
  const float* __restrict__ Bp = Bm + (size_t)(col0 + lr) * K + lk;

  float acc[8][8];
#pragma unroll
  for (int i = 0; i < 8; ++i)
#pragma unroll
    for (int j = 0; j < 8; ++j) acc[i][j] = 0.0f;

  const int nk = K >> 4;

  {
    float4 a0 = *(const float4*)(Ap + 0);
    float4 a1 = *(const float4*)(Ap + 4);
    float4 b0 = *(const float4*)(Bp + 0);
    float4 b1 = *(const float4*)(Bp + 4);
    As[0][lk + 0][lr] = a0.x; As[0][lk + 1][lr] = a0.y; As[0][lk + 2][lr] = a0.z; As[0][lk + 3][lr] = a0.w;
    As[0][lk + 4][lr] = a1.x; As[0][lk + 5][lr] = a1.y; As[0][lk + 6][lr] = a1.z; As[0][lk + 7][lr] = a1.w;
    Bs[0][lk + 0][lr] = b0.x; Bs[0][lk + 1][lr] = b0.y; Bs[0][lk + 2][lr] = b0.z; Bs[0][lk + 3][lr] = b0.w;
    Bs[0][lk + 4][lr] = b1.x; Bs[0][lk + 5][lr] = b1.y; Bs[0][lk + 6][lr] = b1.z; Bs[0][lk + 7][lr] = b1.w;
  }
  __syncthreads();

  for (int t = 0; t < nk; ++t) {
    const int cur = t & 1;
    float4 a0, a1, b0, b1;
    const bool pf = (t + 1 < nk);
    if (pf) {
      const int k0 = (t + 1) << 4;
      a0 = *(const float4*)(Ap + k0);
      a1 = *(const float4*)(Ap + k0 + 4);
      b0 = *(const float4*)(Bp + k0);
      b1 = *(const float4*)(Bp + k0 + 4);
    }
#pragma unroll
    for (int k = 0; k < 16; ++k) {
      float a[8], b[8];
      *(float4*)&a[0] = *(const float4*)&As[cur][k][ty * 8];
      *(float4*)&a[4] = *(const float4*)&As[cur][k][ty * 8 + 4];
      *(float4*)&b[0] = *(const float4*)&Bs[cur][k][tx * 8];
      *(float4*)&b[4] = *(const float4*)&Bs[cur][k][tx * 8 + 4];
#pragma unroll
      for (int i = 0; i < 8; ++i)
#pragma unroll
        for (int j = 0; j < 8; ++j) acc[i][j] += a[i] * b[j];
    }
    if (pf) {
      const int nxt = cur ^ 1;
      As[nxt][lk + 0][lr] = a0.x; As[nxt][lk + 1][lr] = a0.y; As[nxt][lk + 2][lr] = a0.z; As[nxt][lk + 3][lr] = a0.w;
      As[nxt][lk + 4][lr] = a1.x; As[nxt][lk + 5][lr] = a1.y; As[nxt][lk + 6][lr] = a1.z; As[nxt][lk + 7][lr] = a1.w;
      Bs[nxt][lk + 0][lr] = b0.x; Bs[nxt][lk + 1][lr] = b0.y; Bs[nxt][lk + 2][lr] = b0.z; Bs[nxt][lk + 3][lr] = b0.w;
      Bs[nxt][lk + 4][lr] = b1.x; Bs[nxt][lk + 5][lr] = b1.y; Bs[nxt][lk + 6][lr] = b1.z; Bs[nxt][lk + 7][lr] = b1.w;
    }
    __syncthreads();
  }

#pragma unroll
  for (int i = 0; i < 8; ++i) {
    int r = row0 + ty * 8 + i;
    if (r < M) {
#pragma unroll
      for (int j = 0; j < 8; ++j) {
        int c = col0 + tx * 8 + j;
        C[(size_t)r * N + c] = acc[i][j] + bias[c];
      }
    }
  }
}

// ============================ BiLSTM recurrence: PERSISTENT cooperative kernel ============================
// ROUND 9: r8 crashed (hang in the broadcast-release barrier). This round recovers the
// r7 passing structure: the two-level barrier is reverted VERBATIM to r7's proven form
// (leader polls root, stores its own go line, s_sleep(2)). Kept from r8 (data-path only,
// cannot deadlock, bit-exact):
//  - software-pipelined h staging: chunk k+1's 16 L3 loads issued into registers during
//    chunk k's FMA (r7 exposed ~0.8us of L3 latency per 256-k chunk).
//  - pre prefetch for step sl+1 issued before the barrier wait.
// w staged once, c in register, r4 FMA order -> absmax stays 0.0.
__global__ __launch_bounds__(256) void lstm_persist_kernel(
    const float* __restrict__ pre_f, const float* __restrict__ pre_r,
    const float* __restrict__ whh_f, const float* __restrict__ whh_r,
    float* __restrict__ out, float* __restrict__ hbuf, float* __restrict__ cbuf,
    unsigned int* __restrict__ counter, int s0, int Cc, int ep0) {
  const int wg = blockIdx.x;
  const int dir = wg >> 7;
  const int lw = wg & 127;
  const float* __restrict__ pre = dir ? pre_r : pre_f;
  const float* __restrict__ whh = dir ? whh_r : whh_f;
  float* hb = hbuf + (size_t)dir * 2 * B_ * H_;
  float* cb = cbuf + (size_t)dir * B_ * H_;
  const int tid = threadIdx.x;
  const int u0 = lw * 6;

  const int rgrp = tid >> 6;       // wave index == gate 0..3
  const int lane = tid & 63;
  const int kgrp = lane >> 3;      // 0..7 : k-split
  const int bgrp = lane & 7;       // 0..7 : batch quad

  __shared__ float w_lds[24 * 860];   // 82560 B, skewed: this block's 24 gate rows
  __shared__ float h_lds[32 * 284];   // 36352 B, skewed, one 256-k chunk
  __shared__ float g_lds[32][24];

  // barrier lines for this block (r7 layout)
  unsigned int* __restrict__ grp  = counter + ((wg & 7) << 6);        // 8 lines, 256B apart
  unsigned int* __restrict__ root = counter + 512;
  unsigned int* __restrict__ gow  = counter + 576 + ((wg & 7) << 6);  // 8 go lines

  // ---- stage 24 weight rows into skewed LDS ONCE (4608 float4, 18/thread) ----
#pragma unroll
  for (int v = 0; v < 18; ++v) {
    int i = v * 256 + tid;          // 0..4607
    int r24 = i / 192;              // 0..23
    int f4 = i - r24 * 192;         // 0..191
    int k = f4 * 4;
    int grow = (r24 / 6) * H_ + u0 + (r24 % 6);
    *(float4*)&w_lds[r24 * 860 + k + 4 * (k >> 5)] =
        *(const float4*)(whh + (size_t)grow * H_ + k);
  }

  // combine-thread ownership: tid<192 owns (batch cb_, unit cui); c kept in register
  const int cui = tid >> 5;        // 0..5 valid when tid < 192
  const int cb_ = tid & 31;
  float creg = 0.0f;
  if (tid < 192 && s0 > 0) creg = cb[(size_t)cb_ * H_ + u0 + cui];

  // pre for the first step (subsequent steps prefetched before the barrier wait)
  float pre_g0 = 0.f, pre_g1 = 0.f, pre_g2 = 0.f, pre_g3 = 0.f;
  if (tid < 192) {
    const int prow0 = dir ? (Cc - 1) : 0;
    const float* pbt = pre + ((size_t)prow0 * B_ + cb_) * G_;
    pre_g0 = pbt[0 * H_ + u0 + cui];
    pre_g1 = pbt[1 * H_ + u0 + cui];
    pre_g2 = pbt[2 * H_ + u0 + cui];
    pre_g3 = pbt[3 * H_ + u0 + cui];
  }

  const int kl0 = kgrp * 32;

  for (int sl = 0; sl < Cc; ++sl) {
    const int s = s0 + sl;
    const int w = dir ? (W_ - 1 - s) : s;

    float acc[6][4];
#pragma unroll
    for (int r = 0; r < 6; ++r)
#pragma unroll
      for (int j = 0; j < 4; ++j) acc[r][j] = 0.0f;

    if (s > 0) {
      const float* __restrict__ hprev = hb + (size_t)(s & 1) * B_ * H_;

      // issue chunk-0 h loads into registers (agent-scope -> coherence point)
      unsigned long long hq[16];
#pragma unroll
      for (int v = 0; v < 8; ++v) {
        int e = v * 1024 + tid * 4;
        int bb = e >> 8;
        int kk = e & 255;
        const unsigned long long* src =
            (const unsigned long long*)(hprev + (size_t)bb * H_ + kk);
        hq[2 * v]     = __hip_atomic_load(src + 0, __ATOMIC_RELAXED, __HIP_MEMORY_SCOPE_AGENT);
        hq[2 * v + 1] = __hip_atomic_load(src + 1, __ATOMIC_RELAXED, __HIP_MEMORY_SCOPE_AGENT);
      }

      for (int kc = 0; kc < H_; kc += 256) {
        __syncthreads();   // h_lds free (previous chunk consumed / previous step done)
        // write staged registers to LDS (waits on the in-flight loads)
#pragma unroll
        for (int v = 0; v < 8; ++v) {
          int e = v * 1024 + tid * 4;
          int bb = e >> 8;
          int kk = e & 255;
          int off = bb * 284 + kk + 4 * (kk >> 5);
          union { unsigned long long u; float f[2]; } q0, q1;
          q0.u = hq[2 * v]; q1.u = hq[2 * v + 1];
          h_lds[off + 0] = q0.f[0]; h_lds[off + 1] = q0.f[1];
          h_lds[off + 2] = q1.f[0]; h_lds[off + 3] = q1.f[1];
        }
        __syncthreads();   // staging visible
        // issue next chunk's loads now; they fly under this chunk's FMA
        if (kc + 256 < H_) {
#pragma unroll
          for (int v = 0; v < 8; ++v) {
            int e = v * 1024 + tid * 4;
            int bb = e >> 8;
            int kk = e & 255;
            const unsigned long long* src =
                (const unsigned long long*)(hprev + (size_t)bb * H_ + kc + 256 + kk);
            hq[2 * v]     = __hip_atomic_load(src + 0, __ATOMIC_RELAXED, __HIP_MEMORY_SCOPE_AGENT);
            hq[2 * v + 1] = __hip_atomic_load(src + 1, __ATOMIC_RELAXED, __HIP_MEMORY_SCOPE_AGENT);
          }
        }

        const int wbase = kc + kl0;
#pragma unroll 4
        for (int t = 0; t < 8; ++t) {
          const int kl = kl0 + t * 4;
          const int ka = wbase + t * 4;
          const int hoff = kl + 4 * (kl >> 5);
          const int woff = ka + 4 * (ka >> 5);
          float4 h4_0 = *(const float4*)&h_lds[(4 * bgrp + 0) * 284 + hoff];
          float4 h4_1 = *(const float4*)&h_lds[(4 * bgrp + 1) * 284 + hoff];
          float4 h4_2 = *(const float4*)&h_lds[(4 * bgrp + 2) * 284 + hoff];
          float4 h4_3 = *(const float4*)&h_lds[(4 * bgrp + 3) * 284 + hoff];
#pragma unroll
          for (int r = 0; r < 6; ++r) {
            float4 w4 = *(const float4*)&w_lds[(rgrp * 6 + r) * 860 + woff];
            acc[r][0] += h4_0.x * w4.x + h4_0.y * w4.y + h4_0.z * w4.z + h4_0.w * w4.w;
            acc[r][1] += h4_1.x * w4.x + h4_1.y * w4.y + h4_1.z * w4.z + h4_1.w * w4.w;
            acc[r][2] += h4_2.x * w4.x + h4_2.y * w4.y + h4_2.z * w4.z + h4_2.w * w4.w;
            acc[r][3] += h4_3.x * w4.x + h4_3.y * w4.y + h4_3.z * w4.z + h4_3.w * w4.w;
          }
        }
      }

      // ---- reduce the 8-way k-split across kgrp lanes ----
#pragma unroll
      for (int r = 0; r < 6; ++r)
#pragma unroll
        for (int j = 0; j < 4; ++j) {
          float a = acc[r][j];
          a += __shfl_xor(a, 8, 64);
          a += __shfl_xor(a, 16, 64);
          a += __shfl_xor(a, 32, 64);
          acc[r][j] = a;
        }
      if (kgrp == 0) {
#pragma unroll
        for (int r = 0; r < 6; ++r)
#pragma unroll
          for (int j = 0; j < 4; ++j)
            g_lds[4 * bgrp + j][rgrp * 6 + r] = acc[r][j];
      }
    }

    __syncthreads();

    // ---- gate combine ----
    if (tid < 192) {
      float gi = pre_g0, gf = pre_g1, gg = pre_g2, go = pre_g3;
      if (s > 0) {
        gi += g_lds[cb_][cui];
        gf += g_lds[cb_][6 + cui];
        gg += g_lds[cb_][12 + cui];
        go += g_lds[cb_][18 + cui];
      }
      const float si = 1.0f / (1.0f + expf(-gi));
      const float sf = 1.0f / (1.0f + expf(-gf));
      const float so = 1.0f / (1.0f + expf(-go));
      creg = sf * creg + si * tanhf(gg);
      const float h = so * tanhf(creg);
      float* __restrict__ hnext = hb + (size_t)((s + 1) & 1) * B_ * H_;
      __hip_atomic_store(&hnext[(size_t)cb_ * H_ + u0 + cui], h,
                         __ATOMIC_RELAXED, __HIP_MEMORY_SCOPE_AGENT);
      out[((size_t)w * B_ + cb_) * (2 * H_) + (size_t)dir * H_ + u0 + cui] = h;
      // prefetch next step's pre while the barrier wait runs
      if (sl + 1 < Cc) {
        const int prown = dir ? (Cc - 2 - sl) : (sl + 1);
        const float* pbtn = pre + ((size_t)prown * B_ + cb_) * G_;
        pre_g0 = pbtn[0 * H_ + u0 + cui];
        pre_g1 = pbtn[1 * H_ + u0 + cui];
        pre_g2 = pbtn[2 * H_ + u0 + cui];
        pre_g3 = pbtn[3 * H_ + u0 + cui];
      }
    }

    // ---- two-level grid barrier (r7 verbatim: cumulative epochs, leader polls root) ----
    __syncthreads();   // drains vmcnt: h stores are at the coherence point
    if (tid == 0) {
      const unsigned int ep1 = (unsigned int)(ep0 + sl + 1);
      unsigned int old = __hip_atomic_fetch_add(grp, 1u, __ATOMIC_RELAXED, __HIP_MEMORY_SCOPE_AGENT);
      if (old == 32u * ep1 - 1u) {
        // group leader: last arrival of this group this epoch
        __hip_atomic_fetch_add(root, 1u, __ATOMIC_RELAXED, __HIP_MEMORY_SCOPE_AGENT);
        while (__hip_atomic_load(root, __ATOMIC_RELAXED, __HIP_MEMORY_SCOPE_AGENT) < 8u * ep1) {
          __builtin_amdgcn_s_sleep(2);
        }
        __hip_atomic_store(gow, ep1, __ATOMIC_RELAXED, __HIP_MEMORY_SCOPE_AGENT);
      } else {
        while (__hip_atomic_load(gow, __ATOMIC_RELAXED, __HIP_MEMORY_SCOPE_AGENT) < ep1) {
          __builtin_amdgcn_s_sleep(2);
        }
      }
    }
    __syncthreads();
  }

  if (tid < 192) cb[(size_t)cb_ * H_ + u0 + cui] = creg;
}

// ============================ logits + softmax ============================
// h2 is [W][B][2H]; prob is [B][W][NT]
__global__ void logits_softmax_kernel(const float* __restrict__ h2, const float* __restrict__ w_lin,
                                      const float* __restrict__ b_lin, float* __restrict__ prob) {
  int i = blockIdx.x * blockDim.x + threadIdx.x;
  if (i >= B_ * W_) return;
  int b = i / W_, w = i % W_;
  const float4* x = (const float4*)(h2 + ((size_t)w * B_ + b) * (2 * H_));
  const float4* w0 = (const float4*)(w_lin);
  const float4* w1 = (const float4*)(w_lin + 2 * H_);
  float l0 = 0.f, l1 = 0.f;
#pragma unroll 4
  for (int k = 0; k < (2 * H_) / 4; ++k) {
    float4 xv = x[k];
    float4 a = w0[k];
    float4 c = w1[k];
    l0 += xv.x * a.x + xv.y * a.y + xv.z * a.z + xv.w * a.w;
    l1 += xv.x * c.x + xv.y * c.y + xv.z * c.z + xv.w * c.w;
  }
  l0 += b_lin[0];
  l1 += b_lin[1];
  float m = fmaxf(l0, l1);
  float e0 = expf(l0 - m), e1 = expf(l1 - m);
  float s = e0 + e1;
  prob[2 * (size_t)i] = e0 / s;
  prob[2 * (size_t)i + 1] = e1 / s;
}

// ============================ CRF ============================
__device__ __forceinline__ float lse2(float a, float b) {
  float m = fmaxf(a, b);
  return m + logf(expf(a - m) + expf(b - m));
}

__global__ void crf_llh_kernel(const float* __restrict__ emis, const int* __restrict__ tags,
                               const float* __restrict__ start, const float* __restrict__ endv,
                               const float* __restrict__ trans, float* __restrict__ loss_out) {
  int tid = threadIdx.x;  // 64 threads
  float val = 0.f;
  if (tid < B_) {
    const float* e = emis + (size_t)tid * W_ * NT_;
    const int* tg = tags + (size_t)tid * W_;
    const float t00 = trans[0], t01 = trans[1], t10 = trans[2], t11 = trans[3];
    int tp = tg[0];
    float num = start[tp] + e[tp];
    float a0 = start[0] + e[0];
    float a1 = start[1] + e[1];
    for (int s = 1; s < W_; ++s) {
      int ts = tg[s];
      num += e[2 * s + ts] + trans[tp * 2 + ts];
      tp = ts;
      float n0 = lse2(a0 + t00, a1 + t10) + e[2 * s];
      float n1 = lse2(a0 + t01, a1 + t11) + e[2 * s + 1];
      a0 = n0;
      a1 = n1;
    }
    num += endv[tp];
    float logZ = lse2(a0 + endv[0], a1 + endv[1]);
    val = num - logZ;
  }
  for (int off = 32; off > 0; off >>= 1) val += __shfl_down(val, off, 64);
  if (tid == 0) loss_out[0] = -(val / (float)B_);
}

__global__ void crf_decode_kernel(const float* __restrict__ emis,
                                  const float* __restrict__ start, const float* __restrict__ endv,
                                  const float* __restrict__ trans, float* __restrict__ path_out) {
  int b = blockIdx.x * blockDim.x + threadIdx.x;
  if (b >= B_) return;
  const float* e = emis + (size_t)b * W_ * NT_;
  const float t00 = trans[0], t01 = trans[1], t10 = trans[2], t11 = trans[3];
  float s0 = start[0] + e[0];
  float s1 = start[1] + e[1];
  unsigned long long bp0[4] = {0ull, 0ull, 0ull, 0ull};
  unsigned long long bp1[4] = {0ull, 0ull, 0ull, 0ull};
  for (int s = 1; s < W_; ++s) {
    float c00 = s0 + t00, c10 = s1 + t10;  // into j=0
    float c01 = s0 + t01, c11 = s1 + t11;  // into j=1
    int b0 = (c10 > c00) ? 1 : 0;          // argmax: first wins ties
    int b1 = (c11 > c01) ? 1 : 0;
    float m0 = b0 ? c10 : c00;
    float m1 = b1 ? c11 : c01;
    int idx = s - 1;
    bp0[idx >> 6] |= ((unsigned long long)b0) << (idx & 63);
    bp1[idx >> 6] |= ((unsigned long long)b1) << (idx & 63);
    s0 = m0 + e[2 * s];
    s1 = m1 + e[2 * s + 1];
  }
  int tag = ((s1 + endv[1]) > (s0 + endv[0])) ? 1 : 0;
  path_out[(size_t)b * W_ + (W_ - 1)] = (float)tag;
  for (int s = W_ - 2; s >= 0; --s) {
    unsigned long long word = tag ? bp1[s >> 6] : bp0[s >> 6];
    tag = (int)((word >> (s & 63)) & 1ull);
    path_out[(size_t)b * W_ + s] = (float)tag;
  }
}

// ============================ launch ============================
extern "C" void kernel_launch(void* const* d_in, const int* in_sizes, int n_in,
                              void* d_out, int out_size, void* d_ws, size_t ws_size,
                              hipStream_t stream) {
  const float* bert_out = (const float*)d_in[0];
  const int* words_ids = (const int*)d_in[1];
  const int* label_detect = (const int*)d_in[2];
  const float* w_ih_l0 = (const float*)d_in[3];
  const float* w_hh_l0 = (const float*)d_in[4];
  const float* b_l0 = (const float*)d_in[5];
  const float* w_ih_l0r = (const float*)d_in[6];
  const float* w_hh_l0r = (const float*)d_in[7];
  const float* b_l0r = (const float*)d_in[8];
  const float* w_ih_l1 = (const float*)d_in[9];
  const float* w_hh_l1 = (const float*)d_in[10];
  const float* b_l1 = (const float*)d_in[11];
  const float* w_ih_l1r = (const float*)d_in[12];
  const float* w_hh_l1r = (const float*)d_in[13];
  const float* b_l1r = (const float*)d_in[14];
  const float* w_lin = (const float*)d_in[15];
  const float* b_lin = (const float*)d_in[16];
  const float* crf_start = (const float*)d_in[17];
  const float* crf_end = (const float*)d_in[18];
  const float* crf_trans = (const float*)d_in[19];

  float* out = (float*)d_out;
  float* path_out = out;               // 8000
  float* prob_out = out + B_ * W_;     // 16000
  float* loss_out = out + B_ * W_ * 3; // 1

  // Adaptive time-chunk size: largest C (divides 250) whose workspace fits ws_size.
  auto need = [](int c) -> size_t { return 4ull * (24732672ull + 196608ull * (size_t)c); };
  int C = 10;
  if (ws_size >= need(250)) C = 250;
  else if (ws_size >= need(125)) C = 125;
  else if (ws_size >= need(50)) C = 50;
  else if (ws_size >= need(25)) C = 25;
  const int nchunk = W_ / C;
  const size_t CBG = (size_t)C * B_ * G_;

  // workspace layout (floats):
  //   [0 .. 12.288M)         h2 region  (feat [W][B][D] aliases its first 6.144M floats)
  //   [12.288M .. 24.576M)   h1 [W][B][2H]
  //   then preA chunk, preB chunk, hbuf, cbuf, fidx, barrier area (NBAR_ uints)
  float* h2 = (float*)d_ws;
  float* feat = h2;  // alias: feat dead before h2 is written
  float* h1 = h2 + 12288000;
  float* preA = h1 + 12288000;
  float* preB = preA + CBG;
  float* hbuf = preB + CBG;
  float* cbuf = hbuf + 2 * 2 * B_ * H_;
  int* fidx = (int*)(cbuf + 2 * B_ * H_);
  unsigned int* counter = (unsigned int*)(fidx + B_ * W_);

  // 1) first-subtoken gather -> feat [W][B][D]  (also zeroes the barrier area)
  first_idx_kernel<<<(B_ * W_ + 255) / 256, 256, 0, stream>>>(words_ids, fidx, counter);
  gather_kernel<<<(B_ * W_ * (D_ / 4) + 255) / 256, 256, 0, stream>>>(bert_out, fidx, feat);

  const int Mc = C * B_;
  dim3 ggrid((Mc + 127) / 128, G_ / 128);
  int ep = 0;  // barrier epoch base (monotonic across all persistent launches)

  // 2) layer 0: per chunk, fwd+rev input projections then one persistent recurrence launch
  for (int ch = 0; ch < nchunk; ++ch) {
    const int s0 = ch * C;
    gemm_bias_kernel<<<ggrid, 256, 0, stream>>>(feat + (size_t)s0 * B_ * D_, w_ih_l0, b_l0, preA, Mc, G_, D_);
    gemm_bias_kernel<<<ggrid, 256, 0, stream>>>(feat + (size_t)(W_ - C - s0) * B_ * D_, w_ih_l0r, b_l0r, preB, Mc, G_, D_);
    const float* a0 = preA; const float* a1 = preB;
    const float* a2 = w_hh_l0; const float* a3 = w_hh_l0r;
    float* a4 = h1; float* a5 = hbuf; float* a6 = cbuf;
    unsigned int* a7 = counter; int a8 = s0; int a9 = C; int a10 = ep;
    void* args[] = {&a0, &a1, &a2, &a3, &a4, &a5, &a6, &a7, &a8, &a9, &a10};
    hipLaunchCooperativeKernel((void*)lstm_persist_kernel, dim3(256), dim3(256), args, 0, stream);
    ep += C;
  }

  // 3) layer 1 (K = 1536)
  for (int ch = 0; ch < nchunk; ++ch) {
    const int s0 = ch * C;
    gemm_bias_kernel<<<ggrid, 256, 0, stream>>>(h1 + (size_t)s0 * B_ * (2 * H_), w_ih_l1, b_l1, preA, Mc, G_, 2 * H_);
    gemm_bias_kernel<<<ggrid, 256, 0, stream>>>(h1 + (size_t)(W_ - C - s0) * B_ * (2 * H_), w_ih_l1r, b_l1r, preB, Mc, G_, 2 * H_);
    const float* a0 = preA; const float* a1 = preB;
    const float* a2 = w_hh_l1; const float* a3 = w_hh_l1r;
    float* a4 = h2; float* a5 = hbuf; float* a6 = cbuf;
    unsigned int* a7 = counter; int a8 = s0; int a9 = C; int a10 = ep;
    void* args[] = {&a0, &a1, &a2, &a3, &a4, &a5, &a6, &a7, &a8, &a9, &a10};
    hipLaunchCooperativeKernel((void*)lstm_persist_kernel, dim3(256), dim3(256), args, 0, stream);
    ep += C;
  }

  // 4) logits + softmax -> ner_prob (written straight into d_out)
  logits_softmax_kernel<<<(B_ * W_ + 255) / 256, 256, 0, stream>>>(h2, w_lin, b_lin, prob_out);

  // 5) CRF log-likelihood -> loss, Viterbi decode -> path
  crf_llh_kernel<<<1, 64, 0, stream>>>(prob_out, label_detect, crf_start, crf_end, crf_trans, loss_out);
  crf_decode_kernel<<<1, 64, 0, stream>>>(prob_out, crf_start, crf_end, crf_trans, path_out);
}